// Round 11
// baseline (7243.695 us; speedup 1.0000x reference)
//
#include <hip/hip_runtime.h>

#define N_ROWS 32768   // BS*SEQ
#define N_CODES 8192
#define DIM 256
#define KVB 512        // B2 packed [ch || cl]
#define NSTEP 16       // virtual K = 512, BK = 32 (hi.hi then hi.lo)

typedef __attribute__((ext_vector_type(8))) short bf16x8;
typedef __attribute__((ext_vector_type(4))) float f32x4;
typedef __attribute__((ext_vector_type(8))) unsigned short u16x8;

#define GLOAD_LDS16(gp, lp) __builtin_amdgcn_global_load_lds( \
    (const __attribute__((address_space(1))) void*)(gp), \
    (__attribute__((address_space(3))) void*)(lp), 16, 0, 0)

#define RD(base, off) (*reinterpret_cast<const bf16x8*>(&(base)[(off)]))

__device__ __forceinline__ unsigned short f2bf_rne(float f) {
    unsigned int u = __float_as_uint(f);
    unsigned int r = (u + 0x7FFFu + ((u >> 16) & 1u)) >> 16;
    return (unsigned short)r;
}
__device__ __forceinline__ float bf2f(unsigned short h) {
    return __uint_as_float(((unsigned int)h) << 16);
}

// ---------------- per-dim |c| max: 32 partial blocks + deterministic fold ----
__global__ void cmax_kernel(const float* __restrict__ C, float* __restrict__ cmaxp) {
    int t = threadIdx.x;
    float m = 0.f;
    const int k0 = blockIdx.x * 256;
    for (int k = k0; k < k0 + 256; ++k)
        m = fmaxf(m, fabsf(C[(size_t)k * DIM + t]));
    cmaxp[blockIdx.x * DIM + t] = m;
}
__global__ void cmax_fold_kernel(const float* __restrict__ cmaxp,
                                 float* __restrict__ cmax, int* __restrict__ count) {
    int t = threadIdx.x;
    float m = 0.f;
    #pragma unroll
    for (int b = 0; b < 32; ++b) m = fmaxf(m, cmaxp[b * DIM + t]);
    cmax[t] = m;
    if (t == 0) *count = 0;
}

// ---------------- split codebook fp32 -> packed [ch(256) || cl(256)] ---------
__global__ void split_pack_kernel(const float* __restrict__ src,
                                  unsigned short* __restrict__ dst) {
    size_t i = ((size_t)blockIdx.x * blockDim.x + threadIdx.x) * 8;
    int row = (int)(i >> 8);
    int col = (int)(i & 255);
    float4 v0 = *reinterpret_cast<const float4*>(src + i);
    float4 v1 = *reinterpret_cast<const float4*>(src + i + 4);
    float f[8] = {v0.x, v0.y, v0.z, v0.w, v1.x, v1.y, v1.z, v1.w};
    u16x8 h, l;
    #pragma unroll
    for (int j = 0; j < 8; ++j) {
        unsigned short hb = f2bf_rne(f[j]);
        h[j] = hb;
        l[j] = f2bf_rne(f[j] - bf2f(hb));
    }
    *reinterpret_cast<u16x8*>(dst + (size_t)row * KVB + col) = h;
    *reinterpret_cast<u16x8*>(dst + (size_t)row * KVB + 256 + col) = l;
}

// ---------------- split x -> xh (stride 256) + per-row bound Sum|xl|*cmax ----
__global__ void split_x_kernel(const float* __restrict__ src,
                               unsigned short* __restrict__ xh,
                               const float* __restrict__ cmax,
                               float* __restrict__ rowbound) {
    int t = blockIdx.x * blockDim.x + threadIdx.x;
    size_t i = (size_t)t * 8;
    int col = (int)(i & 255);
    float4 v0 = *reinterpret_cast<const float4*>(src + i);
    float4 v1 = *reinterpret_cast<const float4*>(src + i + 4);
    float f[8] = {v0.x, v0.y, v0.z, v0.w, v1.x, v1.y, v1.z, v1.w};
    u16x8 h;
    float s = 0.f;
    #pragma unroll
    for (int j = 0; j < 8; ++j) {
        unsigned short hb = f2bf_rne(f[j]);
        h[j] = hb;
        s += fabsf(f[j] - bf2f(hb)) * cmax[col + j];
    }
    *reinterpret_cast<u16x8*>(xh + i) = h;
    #pragma unroll
    for (int m = 1; m < 32; m <<= 1) s += __shfl_xor(s, m);
    if ((threadIdx.x & 31) == 0) rowbound[t >> 5] = s;
}

// ---------------- c_sq: one wave per code ----------------
__global__ void csq_kernel(const float* __restrict__ C, float* __restrict__ csq) {
    int gtid = blockIdx.x * blockDim.x + threadIdx.x;
    int wave = gtid >> 6;
    int lane = threadIdx.x & 63;
    float4 v = reinterpret_cast<const float4*>(C + (size_t)wave * DIM)[lane];
    float s = v.x * v.x + v.y * v.y + v.z * v.z + v.w * v.w;
    #pragma unroll
    for (int m = 32; m; m >>= 1) s += __shfl_xor(s, m);
    if (lane == 0) csq[wave] = s;
}

// K-offsets (shorts), BK=32: steps 0-7: xh.ch  8-15: xh.cl
__device__ __forceinline__ int AK0(int s) { return (s & 7) * 32; }
__device__ __forceinline__ int BK0(int s) {
    return ((s >= 8) ? 256 : 0) + (s & 7) * 32;
}

// 16 MFMAs of one phase: acc[mb..mb+3][0..3]
#define MFMA16(mb, A0, A1, A2v, A3, B0, B1, B2v, B3)                                \
    acc[mb+0][0] = __builtin_amdgcn_mfma_f32_16x16x32_bf16(A0, B0, acc[mb+0][0], 0, 0, 0); \
    acc[mb+0][1] = __builtin_amdgcn_mfma_f32_16x16x32_bf16(A0, B1, acc[mb+0][1], 0, 0, 0); \
    acc[mb+0][2] = __builtin_amdgcn_mfma_f32_16x16x32_bf16(A0, B2v, acc[mb+0][2], 0, 0, 0); \
    acc[mb+0][3] = __builtin_amdgcn_mfma_f32_16x16x32_bf16(A0, B3, acc[mb+0][3], 0, 0, 0); \
    acc[mb+1][0] = __builtin_amdgcn_mfma_f32_16x16x32_bf16(A1, B0, acc[mb+1][0], 0, 0, 0); \
    acc[mb+1][1] = __builtin_amdgcn_mfma_f32_16x16x32_bf16(A1, B1, acc[mb+1][1], 0, 0, 0); \
    acc[mb+1][2] = __builtin_amdgcn_mfma_f32_16x16x32_bf16(A1, B2v, acc[mb+1][2], 0, 0, 0); \
    acc[mb+1][3] = __builtin_amdgcn_mfma_f32_16x16x32_bf16(A1, B3, acc[mb+1][3], 0, 0, 0); \
    acc[mb+2][0] = __builtin_amdgcn_mfma_f32_16x16x32_bf16(A2v, B0, acc[mb+2][0], 0, 0, 0); \
    acc[mb+2][1] = __builtin_amdgcn_mfma_f32_16x16x32_bf16(A2v, B1, acc[mb+2][1], 0, 0, 0); \
    acc[mb+2][2] = __builtin_amdgcn_mfma_f32_16x16x32_bf16(A2v, B2v, acc[mb+2][2], 0, 0, 0); \
    acc[mb+2][3] = __builtin_amdgcn_mfma_f32_16x16x32_bf16(A2v, B3, acc[mb+2][3], 0, 0, 0); \
    acc[mb+3][0] = __builtin_amdgcn_mfma_f32_16x16x32_bf16(A3, B0, acc[mb+3][0], 0, 0, 0); \
    acc[mb+3][1] = __builtin_amdgcn_mfma_f32_16x16x32_bf16(A3, B1, acc[mb+3][1], 0, 0, 0); \
    acc[mb+3][2] = __builtin_amdgcn_mfma_f32_16x16x32_bf16(A3, B2v, acc[mb+3][2], 0, 0, 0); \
    acc[mb+3][3] = __builtin_amdgcn_mfma_f32_16x16x32_bf16(A3, B3, acc[mb+3][3], 0, 0, 0);

// ---------------- phase 1: r8 schedule (best, 624us), NSTEP=16 ---------------
// grid 4096 = 128 rowblocks x 32 codeblocks, 512 thr = 8 waves (2M x 4N)
// LDS 128 KiB: A slots [4][8192] shorts @0, B slots @32768 shorts.
// Paired-line swizzle (r8-verified): slot8=(q+4*(row&1))^(line&7).
__global__ __launch_bounds__(512, 2) void gemm_argmin_kernel(
        const unsigned short* __restrict__ A2,   // [32768][256] xh
        const unsigned short* __restrict__ B2,   // [8192][512]  [ch||cl]
        const float* __restrict__ csq,
        float4* __restrict__ partials) {         // [32 slots][32768 rows]
    extern __shared__ unsigned short S[];        // 131072 B

    const int tid  = threadIdx.x;
    const int w    = tid >> 6;
    const int l    = tid & 63;
    const int wrM  = w >> 2;
    const int wcN  = w & 3;
    const int lcol = l & 15;
    const int g    = l >> 4;

    const int swz = (blockIdx.x & 7) * 512 + (blockIdx.x >> 3);
    const int rb  = swz & 127;
    const int cbI = swz >> 7;
    const int rowbase  = rb * 256;
    const int codebase = cbI * 256;

    const int pre   = (l & 7) ^ (l >> 3);
    const int stRow = 2 * (l >> 3) + (pre >> 2);
    const int stK   = (pre & 3) * 8;

    const int lbase = (lcol >> 1) * 64 +
                      (((g + ((lcol & 1) << 2)) ^ ((lcol >> 1) & 7)) * 8);
    const int aoff = wrM * 4096 + lbase;   // + m*512
    const int boff = wcN * 2048 + lbase;   // + n*512

    f32x4 acc[8][4];
    #pragma unroll
    for (int m = 0; m < 8; ++m)
        #pragma unroll
        for (int n = 0; n < 4; ++n) acc[m][n] = (f32x4){0.f, 0.f, 0.f, 0.f};

    // prologue: stage steps 0,1,2 into slots 0,1,2
    #pragma unroll
    for (int s0 = 0; s0 < 3; ++s0) {
        const int ak = AK0(s0), bk = BK0(s0);
        #pragma unroll
        for (int i = 0; i < 2; ++i) {
            const int c = 2 * w + i;
            GLOAD_LDS16(A2 + (size_t)(rowbase + c * 16 + stRow) * 256 + ak + stK,
                        &S[s0 * 8192 + c * 512]);
        }
        #pragma unroll
        for (int i = 0; i < 2; ++i) {
            const int c = 2 * w + i;
            GLOAD_LDS16(B2 + (size_t)(codebase + c * 16 + stRow) * KVB + bk + stK,
                        &S[32768 + s0 * 8192 + c * 512]);
        }
    }
    asm volatile("s_waitcnt vmcnt(8)" ::: "memory");
    __builtin_amdgcn_sched_barrier(0);
    __builtin_amdgcn_s_barrier();

    // ph0(0) register prefetch from slot 0
    bf16x8 na0, na1, na2, na3, nb0, nb1, nb2, nb3;
    {
        const unsigned short* Ab = &S[0];
        const unsigned short* Bb = &S[32768];
        na0 = RD(Ab, aoff + 0 * 512); na1 = RD(Ab, aoff + 1 * 512);
        na2 = RD(Ab, aoff + 2 * 512); na3 = RD(Ab, aoff + 3 * 512);
        nb0 = RD(Bb, boff + 0 * 512); nb1 = RD(Bb, boff + 1 * 512);
        nb2 = RD(Bb, boff + 2 * 512); nb3 = RD(Bb, boff + 3 * 512);
    }

    #pragma unroll 1
    for (int so = 0; so < NSTEP; so += 4) {
        #pragma unroll
        for (int k = 0; k < 4; ++k) {
            const int s = so + k;
            const unsigned short* Ab = &S[k * 8192];
            int sn = s + 3; if (sn >= NSTEP) sn -= NSTEP;  // wrap: dead stage
            const int snk = (k + 3) & 3;
            const int ak = AK0(sn), bk = BK0(sn);

            // issue ph1 reads (slot k): a4-7 — stay in flight over ph0 MFMA
            bf16x8 a4 = RD(Ab, aoff + 4 * 512);
            bf16x8 a5 = RD(Ab, aoff + 5 * 512);
            bf16x8 a6 = RD(Ab, aoff + 6 * 512);
            bf16x8 a7 = RD(Ab, aoff + 7 * 512);
            asm volatile("s_waitcnt lgkmcnt(4)" ::: "memory");
            __builtin_amdgcn_sched_barrier(0);
            __builtin_amdgcn_s_setprio(1);
            MFMA16(0, na0, na1, na2, na3, nb0, nb1, nb2, nb3);
            __builtin_amdgcn_s_setprio(0);

            // stage step s+3 into ring slot snk
            #pragma unroll
            for (int i = 0; i < 2; ++i) {
                const int c = 2 * w + i;
                GLOAD_LDS16(A2 + (size_t)(rowbase + c * 16 + stRow) * 256 + ak + stK,
                            &S[snk * 8192 + c * 512]);
            }
            #pragma unroll
            for (int i = 0; i < 2; ++i) {
                const int c = 2 * w + i;
                GLOAD_LDS16(B2 + (size_t)(codebase + c * 16 + stRow) * KVB + bk + stK,
                            &S[32768 + snk * 8192 + c * 512]);
            }

            asm volatile("s_waitcnt lgkmcnt(0)" ::: "memory");
            __builtin_amdgcn_sched_barrier(0);
            __builtin_amdgcn_s_setprio(1);
            MFMA16(4, a4, a5, a6, a7, nb0, nb1, nb2, nb3);
            __builtin_amdgcn_s_setprio(0);

            asm volatile("s_waitcnt vmcnt(8)" ::: "memory");
            __builtin_amdgcn_sched_barrier(0);
            __builtin_amdgcn_s_barrier();

            // prefetch ph0(s+1) regs from just-published slot (k+1)&3
            {
                const unsigned short* Ab2 = &S[((k + 1) & 3) * 8192];
                const unsigned short* Bb2 = &S[32768 + ((k + 1) & 3) * 8192];
                na0 = RD(Ab2, aoff + 0 * 512); na1 = RD(Ab2, aoff + 1 * 512);
                na2 = RD(Ab2, aoff + 2 * 512); na3 = RD(Ab2, aoff + 3 * 512);
                nb0 = RD(Bb2, boff + 0 * 512); nb1 = RD(Bb2, boff + 1 * 512);
                nb2 = RD(Bb2, boff + 2 * 512); nb3 = RD(Bb2, boff + 3 * 512);
            }
        }
    }

    asm volatile("s_waitcnt vmcnt(0) lgkmcnt(0)" ::: "memory");
    __builtin_amdgcn_s_barrier();
    asm volatile("" ::: "memory");

    // ---- epilogue: dist = csq - 2*dot, top-2, fold across 4 N-waves in LDS
    float4* T = reinterpret_cast<float4*>(S);    // [256 rows][4 wc]
    #pragma unroll
    for (int m = 0; m < 8; ++m) {
        #pragma unroll
        for (int r = 0; r < 4; ++r) {
            float v1 = 3.4e38f, v2 = 3.4e38f; int i1 = 0x7fffffff;
            #pragma unroll
            for (int n = 0; n < 4; ++n) {
                int code = codebase + wcN * 64 + n * 16 + lcol;
                float d = fmaf(-2.0f, acc[m][n][r], csq[code]);
                float vmax = fmaxf(d, v1);
                v2 = fminf(v2, vmax);
                bool lt = d < v1;
                v1 = lt ? d : v1;
                i1 = lt ? code : i1;
            }
            #pragma unroll
            for (int mask = 1; mask < 16; mask <<= 1) {
                float ov1 = __shfl_xor(v1, mask);
                float ov2 = __shfl_xor(v2, mask);
                int   oi1 = __shfl_xor(i1, mask);
                float nv2 = fminf(fminf(v2, ov2), fmaxf(v1, ov1));
                bool take = (ov1 < v1) || (ov1 == v1 && oi1 < i1);
                v1 = take ? ov1 : v1;
                i1 = take ? oi1 : i1;
                v2 = nv2;
            }
            if (lcol == ((m * 4 + r) & 15)) {
                int rowL = wrM * 128 + m * 16 + g * 4 + r;
                T[rowL * 4 + wcN] = make_float4(v1, v2, __int_as_float(i1), 0.f);
            }
        }
    }
    __syncthreads();
    if (tid < 256) {
        float v1 = 3.4e38f, v2 = 3.4e38f; int i1 = 0x7fffffff;
        #pragma unroll
        for (int s2 = 0; s2 < 4; ++s2) {
            float4 p = T[tid * 4 + s2];
            int pi = __float_as_int(p.z);
            float nv2 = fminf(fminf(v2, p.y), fmaxf(v1, p.x));
            bool take = (p.x < v1) || (p.x == v1 && pi < i1);
            i1 = take ? pi : i1;
            v1 = fminf(v1, p.x);
            v2 = nv2;
        }
        partials[(size_t)cbI * N_ROWS + rowbase + tid] =
            make_float4(v1, v2, __int_as_float(i1), 0.f);
    }
}

// ---------------- reduce: fold 32 slots; flag iff gap <= 4*RB + slack --------
__global__ void reduce_kernel(const float4* __restrict__ partials,
                              const float* __restrict__ rowbound,
                              int* __restrict__ idx,
                              int* __restrict__ flaglist, int* __restrict__ count) {
    int row = blockIdx.x * 256 + threadIdx.x;
    float v1 = 3.4e38f, v2 = 3.4e38f; int i1 = 0x7fffffff;
    #pragma unroll
    for (int s = 0; s < 32; ++s) {
        float4 p = partials[(size_t)s * N_ROWS + row];
        int pi = __float_as_int(p.z);
        float nv2 = fminf(fminf(v2, p.y), fmaxf(v1, p.x));
        bool take = (p.x < v1) || (p.x == v1 && pi < i1);
        i1 = take ? pi : i1;
        v1 = fminf(v1, p.x);
        v2 = nv2;
    }
    float thr = 4.0f * rowbound[row] + 8e-6f;
    if (v2 - v1 > thr) {
        idx[row] = i1;
    } else {
        int p = atomicAdd(count, 1);
        flaglist[p] = row;
    }
}

// ---------------- exact fp32 recheck: one BLOCK per flagged row --------------
__global__ __launch_bounds__(256) void recheck_kernel(
        const float* __restrict__ X, const float* __restrict__ C,
        const float* __restrict__ csq, const int* __restrict__ flaglist,
        const int* __restrict__ count, int* __restrict__ idx) {
    __shared__ __align__(16) float xs[DIM];
    __shared__ float rv[4];
    __shared__ int   ri[4];
    const int nf = *count;
    const int tid = threadIdx.x;

    for (int b = blockIdx.x; b < nf; b += gridDim.x) {
        const int row = flaglist[b];
        __syncthreads();
        if (tid < 64)
            reinterpret_cast<float4*>(xs)[tid] =
                reinterpret_cast<const float4*>(X + (size_t)row * DIM)[tid];
        __syncthreads();

        float best = 3.4e38f; int bi = 0x7fffffff;
        for (int j = 0; j < 32; j += 2) {
            const int c0 = tid + j * 256;
            const int c1 = c0 + 256;
            const float* p0 = C + (size_t)c0 * DIM;
            const float* p1 = C + (size_t)c1 * DIM;
            float d0 = 0.f, d1 = 0.f;
            #pragma unroll 8
            for (int d = 0; d < DIM; d += 4) {
                float4 a  = *reinterpret_cast<const float4*>(xs + d);
                float4 q0 = *reinterpret_cast<const float4*>(p0 + d);
                float4 q1 = *reinterpret_cast<const float4*>(p1 + d);
                d0 = fmaf(a.x, q0.x, d0); d0 = fmaf(a.y, q0.y, d0);
                d0 = fmaf(a.z, q0.z, d0); d0 = fmaf(a.w, q0.w, d0);
                d1 = fmaf(a.x, q1.x, d1); d1 = fmaf(a.y, q1.y, d1);
                d1 = fmaf(a.z, q1.z, d1); d1 = fmaf(a.w, q1.w, d1);
            }
            float dist0 = fmaf(-2.f, d0, csq[c0]);
            float dist1 = fmaf(-2.f, d1, csq[c1]);
            if (dist0 < best) { best = dist0; bi = c0; }
            if (dist1 < best) { best = dist1; bi = c1; }
        }
        #pragma unroll
        for (int m = 1; m < 64; m <<= 1) {
            float ov = __shfl_xor(best, m);
            int   oi = __shfl_xor(bi, m);
            if (ov < best || (ov == best && oi < bi)) { best = ov; bi = oi; }
        }
        if ((tid & 63) == 0) { rv[tid >> 6] = best; ri[tid >> 6] = bi; }
        __syncthreads();
        if (tid == 0) {
            #pragma unroll
            for (int wv = 1; wv < 4; ++wv) {
                if (rv[wv] < best || (rv[wv] == best && ri[wv] < bi)) {
                    best = rv[wv]; bi = ri[wv];
                }
            }
            idx[row] = bi;
        }
    }
}

// ---------------- gather: one wave per row, write both halves ----------------
__global__ void gather_kernel(const float* __restrict__ C,
                              const int* __restrict__ idx,
                              float* __restrict__ out) {
    const size_t half = (size_t)N_ROWS * DIM;
    int gtid = blockIdx.x * blockDim.x + threadIdx.x;
    int lane = threadIdx.x & 63;
    int wave = gtid >> 6;
    int nwaves = (gridDim.x * blockDim.x) >> 6;
    for (int row = wave; row < N_ROWS; row += nwaves) {
        int id = idx[row];
        float4 v = reinterpret_cast<const float4*>(C + (size_t)id * DIM)[lane];
        reinterpret_cast<float4*>(out + (size_t)row * DIM)[lane] = v;
        reinterpret_cast<float4*>(out + half + (size_t)row * DIM)[lane] = v;
    }
}

extern "C" void kernel_launch(void* const* d_in, const int* in_sizes, int n_in,
                              void* d_out, int out_size, void* d_ws, size_t ws_size,
                              hipStream_t stream) {
    const float* z  = (const float*)d_in[0];   // (32,1024,256) fp32
    const float* cb = (const float*)d_in[1];   // (8192,256)    fp32
    float* out = (float*)d_out;

    // big scratch in d_out (fully overwritten by gather at the end):
    char* sc = (char*)d_out;
    unsigned short* A2 = (unsigned short*)(sc);               // 16,777,216 B (xh)
    unsigned short* B2 = (unsigned short*)(sc + 16777216);    //  8,388,608 B
    float4* partials   = (float4*)(sc + 25165824);            // 16,777,216 B
    float*  rowbound   = (float*)(sc + 41943040);             //    131,072 B
    int*    flags      = (int*)(sc + 42074112);               //    131,072 B

    // small scratch in d_ws (read during/after gather-independent phases):
    float* csq    = (float*)d_ws;                              // 32 KB
    int*   idx    = (int*)((char*)d_ws + 32768);               // 128 KB
    int*   count  = (int*)((char*)d_ws + 163840);              // 4 B
    float* cmaxp  = (float*)((char*)d_ws + 164096);            // 32 KB
    float* cmax   = (float*)((char*)d_ws + 196864);            // 1 KB

    static bool attr_done = false;
    if (!attr_done) {
        hipFuncSetAttribute((const void*)gemm_argmin_kernel,
                            hipFuncAttributeMaxDynamicSharedMemorySize, 131072);
        attr_done = true;
    }

    cmax_kernel<<<32, 256, 0, stream>>>(cb, cmaxp);
    cmax_fold_kernel<<<1, 256, 0, stream>>>(cmaxp, cmax, count);
    split_pack_kernel<<<(N_CODES * DIM) / (256 * 8), 256, 0, stream>>>(cb, B2);
    split_x_kernel<<<(N_ROWS * DIM) / (256 * 8), 256, 0, stream>>>(z, A2, cmax, rowbound);
    csq_kernel<<<(N_CODES * 64) / 256, 256, 0, stream>>>(cb, csq);
    gemm_argmin_kernel<<<4096, 512, 131072, stream>>>(A2, B2, csq, partials);
    reduce_kernel<<<N_ROWS / 256, 256, 0, stream>>>(partials, rowbound, idx, flags, count);
    recheck_kernel<<<512, 256, 0, stream>>>(z, cb, csq, flags, count, idx);
    gather_kernel<<<2048, 256, 0, stream>>>(cb, idx, out);
}

// Round 12
// 562.738 us; speedup vs baseline: 12.8722x; 12.8722x over previous
//
#include <hip/hip_runtime.h>

#define N_ROWS 32768   // BS*SEQ
#define N_CODES 8192
#define DIM 256
#define KVB 512        // B2 packed [ch || cl]
#define NSTEP 16       // virtual K = 512, BK = 32 (xh.ch then xh.cl)

typedef __attribute__((ext_vector_type(8))) short bf16x8;
typedef __attribute__((ext_vector_type(4))) float f32x4;
typedef __attribute__((ext_vector_type(8))) unsigned short u16x8;

#define GLOAD_LDS16(gp, lp) __builtin_amdgcn_global_load_lds( \
    (const __attribute__((address_space(1))) void*)(gp), \
    (__attribute__((address_space(3))) void*)(lp), 16, 0, 0)

#define RD(base, off) (*reinterpret_cast<const bf16x8*>(&(base)[(off)]))

__device__ __forceinline__ unsigned short f2bf_rne(float f) {
    unsigned int u = __float_as_uint(f);
    unsigned int r = (u + 0x7FFFu + ((u >> 16) & 1u)) >> 16;
    return (unsigned short)r;
}
__device__ __forceinline__ float bf2f(unsigned short h) {
    return __uint_as_float(((unsigned int)h) << 16);
}

// ---------------- per-dim |c| max: 32 partial blocks + deterministic fold ----
__global__ void cmax_kernel(const float* __restrict__ C, float* __restrict__ cmaxp) {
    int t = threadIdx.x;
    float m = 0.f;
    const int k0 = blockIdx.x * 256;
    for (int k = k0; k < k0 + 256; ++k)
        m = fmaxf(m, fabsf(C[(size_t)k * DIM + t]));
    cmaxp[blockIdx.x * DIM + t] = m;
}
__global__ void cmax_fold_kernel(const float* __restrict__ cmaxp,
                                 float* __restrict__ cmax) {
    int t = threadIdx.x;
    float m = 0.f;
    #pragma unroll
    for (int b = 0; b < 32; ++b) m = fmaxf(m, cmaxp[b * DIM + t]);
    cmax[t] = m;
}

// ---------------- split codebook fp32 -> packed [ch(256) || cl(256)] ---------
__global__ void split_pack_kernel(const float* __restrict__ src,
                                  unsigned short* __restrict__ dst) {
    size_t i = ((size_t)blockIdx.x * blockDim.x + threadIdx.x) * 8;
    int row = (int)(i >> 8);
    int col = (int)(i & 255);
    float4 v0 = *reinterpret_cast<const float4*>(src + i);
    float4 v1 = *reinterpret_cast<const float4*>(src + i + 4);
    float f[8] = {v0.x, v0.y, v0.z, v0.w, v1.x, v1.y, v1.z, v1.w};
    u16x8 h, l;
    #pragma unroll
    for (int j = 0; j < 8; ++j) {
        unsigned short hb = f2bf_rne(f[j]);
        h[j] = hb;
        l[j] = f2bf_rne(f[j] - bf2f(hb));
    }
    *reinterpret_cast<u16x8*>(dst + (size_t)row * KVB + col) = h;
    *reinterpret_cast<u16x8*>(dst + (size_t)row * KVB + 256 + col) = l;
}

// ---------------- split x -> xh (stride 256) + per-row bound Sum|xl|*cmax ----
__global__ void split_x_kernel(const float* __restrict__ src,
                               unsigned short* __restrict__ xh,
                               const float* __restrict__ cmax,
                               float* __restrict__ rowbound) {
    int t = blockIdx.x * blockDim.x + threadIdx.x;
    size_t i = (size_t)t * 8;
    int col = (int)(i & 255);
    float4 v0 = *reinterpret_cast<const float4*>(src + i);
    float4 v1 = *reinterpret_cast<const float4*>(src + i + 4);
    float f[8] = {v0.x, v0.y, v0.z, v0.w, v1.x, v1.y, v1.z, v1.w};
    u16x8 h;
    float s = 0.f;
    #pragma unroll
    for (int j = 0; j < 8; ++j) {
        unsigned short hb = f2bf_rne(f[j]);
        h[j] = hb;
        s += fabsf(f[j] - bf2f(hb)) * cmax[col + j];
    }
    *reinterpret_cast<u16x8*>(xh + i) = h;
    #pragma unroll
    for (int m = 1; m < 32; m <<= 1) s += __shfl_xor(s, m);
    if ((threadIdx.x & 31) == 0) rowbound[t >> 5] = s;
}

// ---------------- c_sq: one wave per code ----------------
__global__ void csq_kernel(const float* __restrict__ C, float* __restrict__ csq) {
    int gtid = blockIdx.x * blockDim.x + threadIdx.x;
    int wave = gtid >> 6;
    int lane = threadIdx.x & 63;
    float4 v = reinterpret_cast<const float4*>(C + (size_t)wave * DIM)[lane];
    float s = v.x * v.x + v.y * v.y + v.z * v.z + v.w * v.w;
    #pragma unroll
    for (int m = 32; m; m >>= 1) s += __shfl_xor(s, m);
    if (lane == 0) csq[wave] = s;
}

// K-offsets (shorts), BK=32: steps 0-7: xh.ch  8-15: xh.cl
__device__ __forceinline__ int AK0(int s) { return (s & 7) * 32; }
__device__ __forceinline__ int BK0(int s) {
    return ((s >= 8) ? 256 : 0) + (s & 7) * 32;
}

// 16 MFMAs of one phase: acc[mb..mb+3][0..3]
#define MFMA16(mb, A0, A1, A2v, A3, B0, B1, B2v, B3)                                \
    acc[mb+0][0] = __builtin_amdgcn_mfma_f32_16x16x32_bf16(A0, B0, acc[mb+0][0], 0, 0, 0); \
    acc[mb+0][1] = __builtin_amdgcn_mfma_f32_16x16x32_bf16(A0, B1, acc[mb+0][1], 0, 0, 0); \
    acc[mb+0][2] = __builtin_amdgcn_mfma_f32_16x16x32_bf16(A0, B2v, acc[mb+0][2], 0, 0, 0); \
    acc[mb+0][3] = __builtin_amdgcn_mfma_f32_16x16x32_bf16(A0, B3, acc[mb+0][3], 0, 0, 0); \
    acc[mb+1][0] = __builtin_amdgcn_mfma_f32_16x16x32_bf16(A1, B0, acc[mb+1][0], 0, 0, 0); \
    acc[mb+1][1] = __builtin_amdgcn_mfma_f32_16x16x32_bf16(A1, B1, acc[mb+1][1], 0, 0, 0); \
    acc[mb+1][2] = __builtin_amdgcn_mfma_f32_16x16x32_bf16(A1, B2v, acc[mb+1][2], 0, 0, 0); \
    acc[mb+1][3] = __builtin_amdgcn_mfma_f32_16x16x32_bf16(A1, B3, acc[mb+1][3], 0, 0, 0); \
    acc[mb+2][0] = __builtin_amdgcn_mfma_f32_16x16x32_bf16(A2v, B0, acc[mb+2][0], 0, 0, 0); \
    acc[mb+2][1] = __builtin_amdgcn_mfma_f32_16x16x32_bf16(A2v, B1, acc[mb+2][1], 0, 0, 0); \
    acc[mb+2][2] = __builtin_amdgcn_mfma_f32_16x16x32_bf16(A2v, B2v, acc[mb+2][2], 0, 0, 0); \
    acc[mb+2][3] = __builtin_amdgcn_mfma_f32_16x16x32_bf16(A2v, B3, acc[mb+2][3], 0, 0, 0); \
    acc[mb+3][0] = __builtin_amdgcn_mfma_f32_16x16x32_bf16(A3, B0, acc[mb+3][0], 0, 0, 0); \
    acc[mb+3][1] = __builtin_amdgcn_mfma_f32_16x16x32_bf16(A3, B1, acc[mb+3][1], 0, 0, 0); \
    acc[mb+3][2] = __builtin_amdgcn_mfma_f32_16x16x32_bf16(A3, B2v, acc[mb+3][2], 0, 0, 0); \
    acc[mb+3][3] = __builtin_amdgcn_mfma_f32_16x16x32_bf16(A3, B3, acc[mb+3][3], 0, 0, 0);

// ---------------- phase 1: r8 schedule, NSTEP=16, row-major partials ---------
__global__ __launch_bounds__(512, 2) void gemm_argmin_kernel(
        const unsigned short* __restrict__ A2,   // [32768][256] xh
        const unsigned short* __restrict__ B2,   // [8192][512]  [ch||cl]
        const float* __restrict__ csq,
        float4* __restrict__ partials) {         // [32768 rows][32 slots]
    extern __shared__ unsigned short S[];        // 131072 B

    const int tid  = threadIdx.x;
    const int w    = tid >> 6;
    const int l    = tid & 63;
    const int wrM  = w >> 2;
    const int wcN  = w & 3;
    const int lcol = l & 15;
    const int g    = l >> 4;

    const int swz = (blockIdx.x & 7) * 512 + (blockIdx.x >> 3);
    const int rb  = swz & 127;
    const int cbI = swz >> 7;
    const int rowbase  = rb * 256;
    const int codebase = cbI * 256;

    const int pre   = (l & 7) ^ (l >> 3);
    const int stRow = 2 * (l >> 3) + (pre >> 2);
    const int stK   = (pre & 3) * 8;

    const int lbase = (lcol >> 1) * 64 +
                      (((g + ((lcol & 1) << 2)) ^ ((lcol >> 1) & 7)) * 8);
    const int aoff = wrM * 4096 + lbase;   // + m*512
    const int boff = wcN * 2048 + lbase;   // + n*512

    f32x4 acc[8][4];
    #pragma unroll
    for (int m = 0; m < 8; ++m)
        #pragma unroll
        for (int n = 0; n < 4; ++n) acc[m][n] = (f32x4){0.f, 0.f, 0.f, 0.f};

    #pragma unroll
    for (int s0 = 0; s0 < 3; ++s0) {
        const int ak = AK0(s0), bk = BK0(s0);
        #pragma unroll
        for (int i = 0; i < 2; ++i) {
            const int c = 2 * w + i;
            GLOAD_LDS16(A2 + (size_t)(rowbase + c * 16 + stRow) * 256 + ak + stK,
                        &S[s0 * 8192 + c * 512]);
        }
        #pragma unroll
        for (int i = 0; i < 2; ++i) {
            const int c = 2 * w + i;
            GLOAD_LDS16(B2 + (size_t)(codebase + c * 16 + stRow) * KVB + bk + stK,
                        &S[32768 + s0 * 8192 + c * 512]);
        }
    }
    asm volatile("s_waitcnt vmcnt(8)" ::: "memory");
    __builtin_amdgcn_sched_barrier(0);
    __builtin_amdgcn_s_barrier();

    bf16x8 na0, na1, na2, na3, nb0, nb1, nb2, nb3;
    {
        const unsigned short* Ab = &S[0];
        const unsigned short* Bb = &S[32768];
        na0 = RD(Ab, aoff + 0 * 512); na1 = RD(Ab, aoff + 1 * 512);
        na2 = RD(Ab, aoff + 2 * 512); na3 = RD(Ab, aoff + 3 * 512);
        nb0 = RD(Bb, boff + 0 * 512); nb1 = RD(Bb, boff + 1 * 512);
        nb2 = RD(Bb, boff + 2 * 512); nb3 = RD(Bb, boff + 3 * 512);
    }

    #pragma unroll 1
    for (int so = 0; so < NSTEP; so += 4) {
        #pragma unroll
        for (int k = 0; k < 4; ++k) {
            const int s = so + k;
            const unsigned short* Ab = &S[k * 8192];
            int sn = s + 3; if (sn >= NSTEP) sn -= NSTEP;
            const int snk = (k + 3) & 3;
            const int ak = AK0(sn), bk = BK0(sn);

            bf16x8 a4 = RD(Ab, aoff + 4 * 512);
            bf16x8 a5 = RD(Ab, aoff + 5 * 512);
            bf16x8 a6 = RD(Ab, aoff + 6 * 512);
            bf16x8 a7 = RD(Ab, aoff + 7 * 512);
            asm volatile("s_waitcnt lgkmcnt(4)" ::: "memory");
            __builtin_amdgcn_sched_barrier(0);
            __builtin_amdgcn_s_setprio(1);
            MFMA16(0, na0, na1, na2, na3, nb0, nb1, nb2, nb3);
            __builtin_amdgcn_s_setprio(0);

            #pragma unroll
            for (int i = 0; i < 2; ++i) {
                const int c = 2 * w + i;
                GLOAD_LDS16(A2 + (size_t)(rowbase + c * 16 + stRow) * 256 + ak + stK,
                            &S[snk * 8192 + c * 512]);
            }
            #pragma unroll
            for (int i = 0; i < 2; ++i) {
                const int c = 2 * w + i;
                GLOAD_LDS16(B2 + (size_t)(codebase + c * 16 + stRow) * KVB + bk + stK,
                            &S[32768 + snk * 8192 + c * 512]);
            }

            asm volatile("s_waitcnt lgkmcnt(0)" ::: "memory");
            __builtin_amdgcn_sched_barrier(0);
            __builtin_amdgcn_s_setprio(1);
            MFMA16(4, a4, a5, a6, a7, nb0, nb1, nb2, nb3);
            __builtin_amdgcn_s_setprio(0);

            asm volatile("s_waitcnt vmcnt(8)" ::: "memory");
            __builtin_amdgcn_sched_barrier(0);
            __builtin_amdgcn_s_barrier();

            {
                const unsigned short* Ab2 = &S[((k + 1) & 3) * 8192];
                const unsigned short* Bb2 = &S[32768 + ((k + 1) & 3) * 8192];
                na0 = RD(Ab2, aoff + 0 * 512); na1 = RD(Ab2, aoff + 1 * 512);
                na2 = RD(Ab2, aoff + 2 * 512); na3 = RD(Ab2, aoff + 3 * 512);
                nb0 = RD(Bb2, boff + 0 * 512); nb1 = RD(Bb2, boff + 1 * 512);
                nb2 = RD(Bb2, boff + 2 * 512); nb3 = RD(Bb2, boff + 3 * 512);
            }
        }
    }

    asm volatile("s_waitcnt vmcnt(0) lgkmcnt(0)" ::: "memory");
    __builtin_amdgcn_s_barrier();
    asm volatile("" ::: "memory");

    // ---- epilogue: dist = csq - 2*dot, top-2, fold across 4 N-waves in LDS
    float4* T = reinterpret_cast<float4*>(S);    // [256 rows][4 wc]
    #pragma unroll
    for (int m = 0; m < 8; ++m) {
        #pragma unroll
        for (int r = 0; r < 4; ++r) {
            float v1 = 3.4e38f, v2 = 3.4e38f; int i1 = 0x7fffffff;
            #pragma unroll
            for (int n = 0; n < 4; ++n) {
                int code = codebase + wcN * 64 + n * 16 + lcol;
                float d = fmaf(-2.0f, acc[m][n][r], csq[code]);
                float vmax = fmaxf(d, v1);
                v2 = fminf(v2, vmax);
                bool lt = d < v1;
                v1 = lt ? d : v1;
                i1 = lt ? code : i1;
            }
            #pragma unroll
            for (int mask = 1; mask < 16; mask <<= 1) {
                float ov1 = __shfl_xor(v1, mask);
                float ov2 = __shfl_xor(v2, mask);
                int   oi1 = __shfl_xor(i1, mask);
                float nv2 = fminf(fminf(v2, ov2), fmaxf(v1, ov1));
                bool take = (ov1 < v1) || (ov1 == v1 && oi1 < i1);
                v1 = take ? ov1 : v1;
                i1 = take ? oi1 : i1;
                v2 = nv2;
            }
            if (lcol == ((m * 4 + r) & 15)) {
                int rowL = wrM * 128 + m * 16 + g * 4 + r;
                T[rowL * 4 + wcN] = make_float4(v1, v2, __int_as_float(i1), 0.f);
            }
        }
    }
    __syncthreads();
    if (tid < 256) {
        float v1 = 3.4e38f, v2 = 3.4e38f; int i1 = 0x7fffffff;
        #pragma unroll
        for (int s2 = 0; s2 < 4; ++s2) {
            float4 p = T[tid * 4 + s2];
            int pi = __float_as_int(p.z);
            float nv2 = fminf(fminf(v2, p.y), fmaxf(v1, p.x));
            bool take = (p.x < v1) || (p.x == v1 && pi < i1);
            i1 = take ? pi : i1;
            v1 = fminf(v1, p.x);
            v2 = nv2;
        }
        partials[(size_t)(rowbase + tid) * 32 + cbI] =
            make_float4(v1, v2, __int_as_float(i1), 0.f);
    }
}

// ---------------- resolve: one wave per row; in-band candidate refinement ----
// Winner unique in band -> write idx. Else: exact fp32 dot for in-band slot
// winners (coalesced 64-lane dot); full 256-code exact scan for slots whose
// v2 is in band (covers non-winner candidates). Provably exhaustive.
__global__ __launch_bounds__(256) void resolve_kernel(
        const float4* __restrict__ partials,     // [32768][32]
        const float* __restrict__ rowbound,
        const float* __restrict__ X, const float* __restrict__ C,
        const float* __restrict__ csq, int* __restrict__ idx) {
    __shared__ float xs[4][DIM];
    const int lane = threadIdx.x & 63;
    const int wv   = threadIdx.x >> 6;
    const int row  = blockIdx.x * 4 + wv;

    float sv1 = 3.4e38f, sv2 = 3.4e38f; int si1 = 0x7fffffff;
    if (lane < 32) {
        float4 p = partials[(size_t)row * 32 + lane];
        sv1 = p.x; sv2 = p.y; si1 = __float_as_int(p.z);
    }
    float v1g = sv1; int i1g = si1;
    #pragma unroll
    for (int m = 1; m < 64; m <<= 1) {
        float ov = __shfl_xor(v1g, m);
        int   oi = __shfl_xor(i1g, m);
        if (ov < v1g || (ov == v1g && oi < i1g)) { v1g = ov; i1g = oi; }
    }
    const float lim = v1g + 4.0f * rowbound[row] + 1e-5f;
    unsigned long long m1 = __ballot((lane < 32) && (sv1 <= lim));
    unsigned long long m2 = __ballot((lane < 32) && (sv2 <= lim));
    if (__popcll(m1) <= 1 && m2 == 0ull) {
        if (lane == 0) idx[row] = i1g;
        return;
    }

    float4 xv = reinterpret_cast<const float4*>(X + (size_t)row * DIM)[lane];
    reinterpret_cast<float4*>(xs[wv])[lane] = xv;

    float best = 3.4e38f; int bi = 0x7fffffff;
    // (a) exact dots for in-band slot winners
    unsigned long long mm = m1;
    while (mm) {
        int s = __ffsll(mm) - 1; mm &= mm - 1;
        int k = __shfl(si1, s);
        float4 cv = reinterpret_cast<const float4*>(C + (size_t)k * DIM)[lane];
        float d = xv.x * cv.x;
        d = fmaf(xv.y, cv.y, d);
        d = fmaf(xv.z, cv.z, d);
        d = fmaf(xv.w, cv.w, d);
        #pragma unroll
        for (int m = 1; m < 64; m <<= 1) d += __shfl_xor(d, m);
        float dist = fmaf(-2.f, d, csq[k]);
        if (dist < best || (dist == best && k < bi)) { best = dist; bi = k; }
    }
    // (b) full exact scan of slots with v2 in band (4 codes/lane, ILP-4)
    mm = m2;
    while (mm) {
        int s = __ffsll(mm) - 1; mm &= mm - 1;
        const int k0 = s * 256 + lane;
        const float* c0 = C + (size_t)k0 * DIM;
        float d0 = 0.f, d1 = 0.f, d2 = 0.f, d3 = 0.f;
        #pragma unroll 8
        for (int dd = 0; dd < DIM; dd += 4) {
            float4 a  = *reinterpret_cast<const float4*>(&xs[wv][dd]);
            float4 q0 = *reinterpret_cast<const float4*>(c0 + dd);
            float4 q1 = *reinterpret_cast<const float4*>(c0 + 64 * DIM + dd);
            float4 q2 = *reinterpret_cast<const float4*>(c0 + 128 * DIM + dd);
            float4 q3 = *reinterpret_cast<const float4*>(c0 + 192 * DIM + dd);
            d0 = fmaf(a.x,q0.x,d0); d0 = fmaf(a.y,q0.y,d0); d0 = fmaf(a.z,q0.z,d0); d0 = fmaf(a.w,q0.w,d0);
            d1 = fmaf(a.x,q1.x,d1); d1 = fmaf(a.y,q1.y,d1); d1 = fmaf(a.z,q1.z,d1); d1 = fmaf(a.w,q1.w,d1);
            d2 = fmaf(a.x,q2.x,d2); d2 = fmaf(a.y,q2.y,d2); d2 = fmaf(a.z,q2.z,d2); d2 = fmaf(a.w,q2.w,d2);
            d3 = fmaf(a.x,q3.x,d3); d3 = fmaf(a.y,q3.y,d3); d3 = fmaf(a.z,q3.z,d3); d3 = fmaf(a.w,q3.w,d3);
        }
        float e0 = fmaf(-2.f, d0, csq[k0]);
        float e1 = fmaf(-2.f, d1, csq[k0 + 64]);
        float e2 = fmaf(-2.f, d2, csq[k0 + 128]);
        float e3 = fmaf(-2.f, d3, csq[k0 + 192]);
        if (e0 < best || (e0 == best && (k0      ) < bi)) { best = e0; bi = k0; }
        if (e1 < best || (e1 == best && (k0 +  64) < bi)) { best = e1; bi = k0 + 64; }
        if (e2 < best || (e2 == best && (k0 + 128) < bi)) { best = e2; bi = k0 + 128; }
        if (e3 < best || (e3 == best && (k0 + 192) < bi)) { best = e3; bi = k0 + 192; }
    }
    #pragma unroll
    for (int m = 1; m < 64; m <<= 1) {
        float ov = __shfl_xor(best, m);
        int   oi = __shfl_xor(bi, m);
        if (ov < best || (ov == best && oi < bi)) { best = ov; bi = oi; }
    }
    if (lane == 0) idx[row] = bi;
}

// ---------------- gather: one wave per row, write both halves ----------------
__global__ void gather_kernel(const float* __restrict__ C,
                              const int* __restrict__ idx,
                              float* __restrict__ out) {
    const size_t half = (size_t)N_ROWS * DIM;
    int gtid = blockIdx.x * blockDim.x + threadIdx.x;
    int lane = threadIdx.x & 63;
    int wave = gtid >> 6;
    int nwaves = (gridDim.x * blockDim.x) >> 6;
    for (int row = wave; row < N_ROWS; row += nwaves) {
        int id = idx[row];
        float4 v = reinterpret_cast<const float4*>(C + (size_t)id * DIM)[lane];
        reinterpret_cast<float4*>(out + (size_t)row * DIM)[lane] = v;
        reinterpret_cast<float4*>(out + half + (size_t)row * DIM)[lane] = v;
    }
}

extern "C" void kernel_launch(void* const* d_in, const int* in_sizes, int n_in,
                              void* d_out, int out_size, void* d_ws, size_t ws_size,
                              hipStream_t stream) {
    const float* z  = (const float*)d_in[0];   // (32,1024,256) fp32
    const float* cb = (const float*)d_in[1];   // (8192,256)    fp32
    float* out = (float*)d_out;

    // big scratch in d_out (fully overwritten by gather at the end):
    char* sc = (char*)d_out;
    unsigned short* A2 = (unsigned short*)(sc);               // 16,777,216 B (xh)
    unsigned short* B2 = (unsigned short*)(sc + 16777216);    //  8,388,608 B
    float4* partials   = (float4*)(sc + 25165824);            // 16,777,216 B
    float*  rowbound   = (float*)(sc + 41943040);             //    131,072 B

    // small scratch in d_ws:
    float* csq    = (float*)d_ws;                              // 32 KB
    int*   idx    = (int*)((char*)d_ws + 32768);               // 128 KB
    float* cmaxp  = (float*)((char*)d_ws + 163840);            // 32 KB
    float* cmax   = (float*)((char*)d_ws + 196608);            // 1 KB

    static bool attr_done = false;
    if (!attr_done) {
        hipFuncSetAttribute((const void*)gemm_argmin_kernel,
                            hipFuncAttributeMaxDynamicSharedMemorySize, 131072);
        attr_done = true;
    }

    cmax_kernel<<<32, 256, 0, stream>>>(cb, cmaxp);
    cmax_fold_kernel<<<1, 256, 0, stream>>>(cmaxp, cmax);
    split_pack_kernel<<<(N_CODES * DIM) / (256 * 8), 256, 0, stream>>>(cb, B2);
    split_x_kernel<<<(N_ROWS * DIM) / (256 * 8), 256, 0, stream>>>(z, A2, cmax, rowbound);
    csq_kernel<<<(N_CODES * 64) / 256, 256, 0, stream>>>(cb, csq);
    gemm_argmin_kernel<<<4096, 512, 131072, stream>>>(A2, B2, csq, partials);
    resolve_kernel<<<N_ROWS / 4, 256, 0, stream>>>(partials, rowbound, z, cb, csq, idx);
    gather_kernel<<<2048, 256, 0, stream>>>(cb, idx, out);
}

// Round 13
// 497.691 us; speedup vs baseline: 14.5546x; 1.1307x over previous
//
#include <hip/hip_runtime.h>

#define N_ROWS 32768   // BS*SEQ
#define N_CODES 8192
#define DIM 256
#define NSTEP 8        // virtual K = 256, BK = 32 (xh.ch only)

typedef __attribute__((ext_vector_type(8))) short bf16x8;
typedef __attribute__((ext_vector_type(4))) float f32x4;
typedef __attribute__((ext_vector_type(8))) unsigned short u16x8;

#define GLOAD_LDS16(gp, lp) __builtin_amdgcn_global_load_lds( \
    (const __attribute__((address_space(1))) void*)(gp), \
    (__attribute__((address_space(3))) void*)(lp), 16, 0, 0)

#define RD(base, off) (*reinterpret_cast<const bf16x8*>(&(base)[(off)]))

__device__ __forceinline__ unsigned short f2bf_rne(float f) {
    unsigned int u = __float_as_uint(f);
    unsigned int r = (u + 0x7FFFu + ((u >> 16) & 1u)) >> 16;
    return (unsigned short)r;
}
__device__ __forceinline__ float bf2f(unsigned short h) {
    return __uint_as_float(((unsigned int)h) << 16);
}

// ------- per-dim max|c| and max|c - bf16(c)|: 32 partials + deterministic fold
__global__ void cmax_kernel(const float* __restrict__ C,
                            float* __restrict__ cmaxp, float* __restrict__ clmaxp) {
    int t = threadIdx.x;
    float m = 0.f, ml = 0.f;
    const int k0 = blockIdx.x * 256;
    for (int k = k0; k < k0 + 256; ++k) {
        float c = C[(size_t)k * DIM + t];
        m = fmaxf(m, fabsf(c));
        ml = fmaxf(ml, fabsf(c - bf2f(f2bf_rne(c))));
    }
    cmaxp[blockIdx.x * DIM + t] = m;
    clmaxp[blockIdx.x * DIM + t] = ml;
}
__global__ void cmax_fold_kernel(const float* __restrict__ cmaxp,
                                 const float* __restrict__ clmaxp,
                                 float* __restrict__ cmax, float* __restrict__ clmax) {
    int t = threadIdx.x;
    float m = 0.f, ml = 0.f;
    #pragma unroll
    for (int b = 0; b < 32; ++b) {
        m = fmaxf(m, cmaxp[b * DIM + t]);
        ml = fmaxf(ml, clmaxp[b * DIM + t]);
    }
    cmax[t] = m;
    clmax[t] = ml;
}

// ---------------- split codebook fp32 -> ch (bf16, stride 256) ---------------
__global__ void split_pack_kernel(const float* __restrict__ src,
                                  unsigned short* __restrict__ dst) {
    size_t i = ((size_t)blockIdx.x * blockDim.x + threadIdx.x) * 8;
    float4 v0 = *reinterpret_cast<const float4*>(src + i);
    float4 v1 = *reinterpret_cast<const float4*>(src + i + 4);
    float f[8] = {v0.x, v0.y, v0.z, v0.w, v1.x, v1.y, v1.z, v1.w};
    u16x8 h;
    #pragma unroll
    for (int j = 0; j < 8; ++j) h[j] = f2bf_rne(f[j]);
    *reinterpret_cast<u16x8*>(dst + i) = h;
}

// -------- split x -> xh + per-row bound Sum|xl|*cmax + Sum|xh|*clmax ---------
__global__ void split_x_kernel(const float* __restrict__ src,
                               unsigned short* __restrict__ xh,
                               const float* __restrict__ cmax,
                               const float* __restrict__ clmax,
                               float* __restrict__ rowbound) {
    int t = blockIdx.x * blockDim.x + threadIdx.x;
    size_t i = (size_t)t * 8;
    int col = (int)(i & 255);
    float4 v0 = *reinterpret_cast<const float4*>(src + i);
    float4 v1 = *reinterpret_cast<const float4*>(src + i + 4);
    float f[8] = {v0.x, v0.y, v0.z, v0.w, v1.x, v1.y, v1.z, v1.w};
    u16x8 h;
    float s = 0.f;
    #pragma unroll
    for (int j = 0; j < 8; ++j) {
        unsigned short hb = f2bf_rne(f[j]);
        h[j] = hb;
        float hv = bf2f(hb);
        s += fabsf(f[j] - hv) * cmax[col + j] + fabsf(hv) * clmax[col + j];
    }
    *reinterpret_cast<u16x8*>(xh + i) = h;
    #pragma unroll
    for (int m = 1; m < 32; m <<= 1) s += __shfl_xor(s, m);
    if ((threadIdx.x & 31) == 0) rowbound[t >> 5] = s * 1.01f;
}

// ---------------- c_sq: one wave per code ----------------
__global__ void csq_kernel(const float* __restrict__ C, float* __restrict__ csq) {
    int gtid = blockIdx.x * blockDim.x + threadIdx.x;
    int wave = gtid >> 6;
    int lane = threadIdx.x & 63;
    float4 v = reinterpret_cast<const float4*>(C + (size_t)wave * DIM)[lane];
    float s = v.x * v.x + v.y * v.y + v.z * v.z + v.w * v.w;
    #pragma unroll
    for (int m = 32; m; m >>= 1) s += __shfl_xor(s, m);
    if (lane == 0) csq[wave] = s;
}

// K-offset (shorts), BK=32, 8 steps over K=256
__device__ __forceinline__ int AK0(int s) { return (s & 7) * 32; }

// 16 MFMAs of one phase: acc[mb..mb+3][0..3]
#define MFMA16(mb, A0, A1, A2v, A3, B0, B1, B2v, B3)                                \
    acc[mb+0][0] = __builtin_amdgcn_mfma_f32_16x16x32_bf16(A0, B0, acc[mb+0][0], 0, 0, 0); \
    acc[mb+0][1] = __builtin_amdgcn_mfma_f32_16x16x32_bf16(A0, B1, acc[mb+0][1], 0, 0, 0); \
    acc[mb+0][2] = __builtin_amdgcn_mfma_f32_16x16x32_bf16(A0, B2v, acc[mb+0][2], 0, 0, 0); \
    acc[mb+0][3] = __builtin_amdgcn_mfma_f32_16x16x32_bf16(A0, B3, acc[mb+0][3], 0, 0, 0); \
    acc[mb+1][0] = __builtin_amdgcn_mfma_f32_16x16x32_bf16(A1, B0, acc[mb+1][0], 0, 0, 0); \
    acc[mb+1][1] = __builtin_amdgcn_mfma_f32_16x16x32_bf16(A1, B1, acc[mb+1][1], 0, 0, 0); \
    acc[mb+1][2] = __builtin_amdgcn_mfma_f32_16x16x32_bf16(A1, B2v, acc[mb+1][2], 0, 0, 0); \
    acc[mb+1][3] = __builtin_amdgcn_mfma_f32_16x16x32_bf16(A1, B3, acc[mb+1][3], 0, 0, 0); \
    acc[mb+2][0] = __builtin_amdgcn_mfma_f32_16x16x32_bf16(A2v, B0, acc[mb+2][0], 0, 0, 0); \
    acc[mb+2][1] = __builtin_amdgcn_mfma_f32_16x16x32_bf16(A2v, B1, acc[mb+2][1], 0, 0, 0); \
    acc[mb+2][2] = __builtin_amdgcn_mfma_f32_16x16x32_bf16(A2v, B2v, acc[mb+2][2], 0, 0, 0); \
    acc[mb+2][3] = __builtin_amdgcn_mfma_f32_16x16x32_bf16(A2v, B3, acc[mb+2][3], 0, 0, 0); \
    acc[mb+3][0] = __builtin_amdgcn_mfma_f32_16x16x32_bf16(A3, B0, acc[mb+3][0], 0, 0, 0); \
    acc[mb+3][1] = __builtin_amdgcn_mfma_f32_16x16x32_bf16(A3, B1, acc[mb+3][1], 0, 0, 0); \
    acc[mb+3][2] = __builtin_amdgcn_mfma_f32_16x16x32_bf16(A3, B2v, acc[mb+3][2], 0, 0, 0); \
    acc[mb+3][3] = __builtin_amdgcn_mfma_f32_16x16x32_bf16(A3, B3, acc[mb+3][3], 0, 0, 0);

// ---------------- phase 1: r8 schedule, NSTEP=8 (xh.ch only) -----------------
__global__ __launch_bounds__(512, 2) void gemm_argmin_kernel(
        const unsigned short* __restrict__ A2,   // [32768][256] xh
        const unsigned short* __restrict__ B2,   // [8192][256]  ch
        const float* __restrict__ csq,
        float4* __restrict__ partials) {         // [32768 rows][32 slots]
    extern __shared__ unsigned short S[];        // 131072 B

    const int tid  = threadIdx.x;
    const int w    = tid >> 6;
    const int l    = tid & 63;
    const int wrM  = w >> 2;
    const int wcN  = w & 3;
    const int lcol = l & 15;
    const int g    = l >> 4;

    const int swz = (blockIdx.x & 7) * 512 + (blockIdx.x >> 3);
    const int rb  = swz & 127;
    const int cbI = swz >> 7;
    const int rowbase  = rb * 256;
    const int codebase = cbI * 256;

    const int pre   = (l & 7) ^ (l >> 3);
    const int stRow = 2 * (l >> 3) + (pre >> 2);
    const int stK   = (pre & 3) * 8;

    const int lbase = (lcol >> 1) * 64 +
                      (((g + ((lcol & 1) << 2)) ^ ((lcol >> 1) & 7)) * 8);
    const int aoff = wrM * 4096 + lbase;   // + m*512
    const int boff = wcN * 2048 + lbase;   // + n*512

    f32x4 acc[8][4];
    #pragma unroll
    for (int m = 0; m < 8; ++m)
        #pragma unroll
        for (int n = 0; n < 4; ++n) acc[m][n] = (f32x4){0.f, 0.f, 0.f, 0.f};

    #pragma unroll
    for (int s0 = 0; s0 < 3; ++s0) {
        const int ak = AK0(s0);
        #pragma unroll
        for (int i = 0; i < 2; ++i) {
            const int c = 2 * w + i;
            GLOAD_LDS16(A2 + (size_t)(rowbase + c * 16 + stRow) * 256 + ak + stK,
                        &S[s0 * 8192 + c * 512]);
        }
        #pragma unroll
        for (int i = 0; i < 2; ++i) {
            const int c = 2 * w + i;
            GLOAD_LDS16(B2 + (size_t)(codebase + c * 16 + stRow) * 256 + ak + stK,
                        &S[32768 + s0 * 8192 + c * 512]);
        }
    }
    asm volatile("s_waitcnt vmcnt(8)" ::: "memory");
    __builtin_amdgcn_sched_barrier(0);
    __builtin_amdgcn_s_barrier();

    bf16x8 na0, na1, na2, na3, nb0, nb1, nb2, nb3;
    {
        const unsigned short* Ab = &S[0];
        const unsigned short* Bb = &S[32768];
        na0 = RD(Ab, aoff + 0 * 512); na1 = RD(Ab, aoff + 1 * 512);
        na2 = RD(Ab, aoff + 2 * 512); na3 = RD(Ab, aoff + 3 * 512);
        nb0 = RD(Bb, boff + 0 * 512); nb1 = RD(Bb, boff + 1 * 512);
        nb2 = RD(Bb, boff + 2 * 512); nb3 = RD(Bb, boff + 3 * 512);
    }

    #pragma unroll 1
    for (int so = 0; so < NSTEP; so += 4) {
        #pragma unroll
        for (int k = 0; k < 4; ++k) {
            const int s = so + k;
            const unsigned short* Ab = &S[k * 8192];
            int sn = s + 3; if (sn >= NSTEP) sn -= NSTEP;  // wrap: dead stage
            const int snk = (k + 3) & 3;
            const int ak = AK0(sn);

            bf16x8 a4 = RD(Ab, aoff + 4 * 512);
            bf16x8 a5 = RD(Ab, aoff + 5 * 512);
            bf16x8 a6 = RD(Ab, aoff + 6 * 512);
            bf16x8 a7 = RD(Ab, aoff + 7 * 512);
            asm volatile("s_waitcnt lgkmcnt(4)" ::: "memory");
            __builtin_amdgcn_sched_barrier(0);
            __builtin_amdgcn_s_setprio(1);
            MFMA16(0, na0, na1, na2, na3, nb0, nb1, nb2, nb3);
            __builtin_amdgcn_s_setprio(0);

            #pragma unroll
            for (int i = 0; i < 2; ++i) {
                const int c = 2 * w + i;
                GLOAD_LDS16(A2 + (size_t)(rowbase + c * 16 + stRow) * 256 + ak + stK,
                            &S[snk * 8192 + c * 512]);
            }
            #pragma unroll
            for (int i = 0; i < 2; ++i) {
                const int c = 2 * w + i;
                GLOAD_LDS16(B2 + (size_t)(codebase + c * 16 + stRow) * 256 + ak + stK,
                            &S[32768 + snk * 8192 + c * 512]);
            }

            asm volatile("s_waitcnt lgkmcnt(0)" ::: "memory");
            __builtin_amdgcn_sched_barrier(0);
            __builtin_amdgcn_s_setprio(1);
            MFMA16(4, a4, a5, a6, a7, nb0, nb1, nb2, nb3);
            __builtin_amdgcn_s_setprio(0);

            asm volatile("s_waitcnt vmcnt(8)" ::: "memory");
            __builtin_amdgcn_sched_barrier(0);
            __builtin_amdgcn_s_barrier();

            {
                const unsigned short* Ab2 = &S[((k + 1) & 3) * 8192];
                const unsigned short* Bb2 = &S[32768 + ((k + 1) & 3) * 8192];
                na0 = RD(Ab2, aoff + 0 * 512); na1 = RD(Ab2, aoff + 1 * 512);
                na2 = RD(Ab2, aoff + 2 * 512); na3 = RD(Ab2, aoff + 3 * 512);
                nb0 = RD(Bb2, boff + 0 * 512); nb1 = RD(Bb2, boff + 1 * 512);
                nb2 = RD(Bb2, boff + 2 * 512); nb3 = RD(Bb2, boff + 3 * 512);
            }
        }
    }

    asm volatile("s_waitcnt vmcnt(0) lgkmcnt(0)" ::: "memory");
    __builtin_amdgcn_s_barrier();
    asm volatile("" ::: "memory");

    // ---- epilogue: dist = csq - 2*dot, top-2, fold across 4 N-waves in LDS
    float4* T = reinterpret_cast<float4*>(S);    // [256 rows][4 wc]
    #pragma unroll
    for (int m = 0; m < 8; ++m) {
        #pragma unroll
        for (int r = 0; r < 4; ++r) {
            float v1 = 3.4e38f, v2 = 3.4e38f; int i1 = 0x7fffffff;
            #pragma unroll
            for (int n = 0; n < 4; ++n) {
                int code = codebase + wcN * 64 + n * 16 + lcol;
                float d = fmaf(-2.0f, acc[m][n][r], csq[code]);
                float vmax = fmaxf(d, v1);
                v2 = fminf(v2, vmax);
                bool lt = d < v1;
                v1 = lt ? d : v1;
                i1 = lt ? code : i1;
            }
            #pragma unroll
            for (int mask = 1; mask < 16; mask <<= 1) {
                float ov1 = __shfl_xor(v1, mask);
                float ov2 = __shfl_xor(v2, mask);
                int   oi1 = __shfl_xor(i1, mask);
                float nv2 = fminf(fminf(v2, ov2), fmaxf(v1, ov1));
                bool take = (ov1 < v1) || (ov1 == v1 && oi1 < i1);
                v1 = take ? ov1 : v1;
                i1 = take ? oi1 : i1;
                v2 = nv2;
            }
            if (lcol == ((m * 4 + r) & 15)) {
                int rowL = wrM * 128 + m * 16 + g * 4 + r;
                T[rowL * 4 + wcN] = make_float4(v1, v2, __int_as_float(i1), 0.f);
            }
        }
    }
    __syncthreads();
    if (tid < 256) {
        float v1 = 3.4e38f, v2 = 3.4e38f; int i1 = 0x7fffffff;
        #pragma unroll
        for (int s2 = 0; s2 < 4; ++s2) {
            float4 p = T[tid * 4 + s2];
            int pi = __float_as_int(p.z);
            float nv2 = fminf(fminf(v2, p.y), fmaxf(v1, p.x));
            bool take = (p.x < v1) || (p.x == v1 && pi < i1);
            i1 = take ? pi : i1;
            v1 = fminf(v1, p.x);
            v2 = nv2;
        }
        partials[(size_t)(rowbase + tid) * 32 + cbI] =
            make_float4(v1, v2, __int_as_float(i1), 0.f);
    }
}

// ---------------- resolve: one wave per row; in-band candidate refinement ----
__global__ __launch_bounds__(256) void resolve_kernel(
        const float4* __restrict__ partials,     // [32768][32]
        const float* __restrict__ rowbound,
        const float* __restrict__ X, const float* __restrict__ C,
        const float* __restrict__ csq, int* __restrict__ idx) {
    __shared__ float xs[4][DIM];
    const int lane = threadIdx.x & 63;
    const int wv   = threadIdx.x >> 6;
    const int row  = blockIdx.x * 4 + wv;

    float sv1 = 3.4e38f, sv2 = 3.4e38f; int si1 = 0x7fffffff;
    if (lane < 32) {
        float4 p = partials[(size_t)row * 32 + lane];
        sv1 = p.x; sv2 = p.y; si1 = __float_as_int(p.z);
    }
    float v1g = sv1; int i1g = si1;
    #pragma unroll
    for (int m = 1; m < 64; m <<= 1) {
        float ov = __shfl_xor(v1g, m);
        int   oi = __shfl_xor(i1g, m);
        if (ov < v1g || (ov == v1g && oi < i1g)) { v1g = ov; i1g = oi; }
    }
    const float lim = v1g + 4.0f * rowbound[row] + 1e-5f;
    unsigned long long m1 = __ballot((lane < 32) && (sv1 <= lim));
    unsigned long long m2 = __ballot((lane < 32) && (sv2 <= lim));
    if (__popcll(m1) <= 1 && m2 == 0ull) {
        if (lane == 0) idx[row] = i1g;
        return;
    }

    float4 xv = reinterpret_cast<const float4*>(X + (size_t)row * DIM)[lane];
    reinterpret_cast<float4*>(xs[wv])[lane] = xv;

    float best = 3.4e38f; int bi = 0x7fffffff;
    // (a) exact dots for in-band slot winners
    unsigned long long mm = m1;
    while (mm) {
        int s = __ffsll(mm) - 1; mm &= mm - 1;
        int k = __shfl(si1, s);
        float4 cv = reinterpret_cast<const float4*>(C + (size_t)k * DIM)[lane];
        float d = xv.x * cv.x;
        d = fmaf(xv.y, cv.y, d);
        d = fmaf(xv.z, cv.z, d);
        d = fmaf(xv.w, cv.w, d);
        #pragma unroll
        for (int m = 1; m < 64; m <<= 1) d += __shfl_xor(d, m);
        float dist = fmaf(-2.f, d, csq[k]);
        if (dist < best || (dist == best && k < bi)) { best = dist; bi = k; }
    }
    // (b) full exact scan of slots with v2 in band (4 codes/lane, ILP-4)
    mm = m2;
    while (mm) {
        int s = __ffsll(mm) - 1; mm &= mm - 1;
        const int k0 = s * 256 + lane;
        const float* c0 = C + (size_t)k0 * DIM;
        float d0 = 0.f, d1 = 0.f, d2 = 0.f, d3 = 0.f;
        #pragma unroll 8
        for (int dd = 0; dd < DIM; dd += 4) {
            float4 a  = *reinterpret_cast<const float4*>(&xs[wv][dd]);
            float4 q0 = *reinterpret_cast<const float4*>(c0 + dd);
            float4 q1 = *reinterpret_cast<const float4*>(c0 + 64 * DIM + dd);
            float4 q2 = *reinterpret_cast<const float4*>(c0 + 128 * DIM + dd);
            float4 q3 = *reinterpret_cast<const float4*>(c0 + 192 * DIM + dd);
            d0 = fmaf(a.x,q0.x,d0); d0 = fmaf(a.y,q0.y,d0); d0 = fmaf(a.z,q0.z,d0); d0 = fmaf(a.w,q0.w,d0);
            d1 = fmaf(a.x,q1.x,d1); d1 = fmaf(a.y,q1.y,d1); d1 = fmaf(a.z,q1.z,d1); d1 = fmaf(a.w,q1.w,d1);
            d2 = fmaf(a.x,q2.x,d2); d2 = fmaf(a.y,q2.y,d2); d2 = fmaf(a.z,q2.z,d2); d2 = fmaf(a.w,q2.w,d2);
            d3 = fmaf(a.x,q3.x,d3); d3 = fmaf(a.y,q3.y,d3); d3 = fmaf(a.z,q3.z,d3); d3 = fmaf(a.w,q3.w,d3);
        }
        float e0 = fmaf(-2.f, d0, csq[k0]);
        float e1 = fmaf(-2.f, d1, csq[k0 + 64]);
        float e2 = fmaf(-2.f, d2, csq[k0 + 128]);
        float e3 = fmaf(-2.f, d3, csq[k0 + 192]);
        if (e0 < best || (e0 == best && (k0      ) < bi)) { best = e0; bi = k0; }
        if (e1 < best || (e1 == best && (k0 +  64) < bi)) { best = e1; bi = k0 + 64; }
        if (e2 < best || (e2 == best && (k0 + 128) < bi)) { best = e2; bi = k0 + 128; }
        if (e3 < best || (e3 == best && (k0 + 192) < bi)) { best = e3; bi = k0 + 192; }
    }
    #pragma unroll
    for (int m = 1; m < 64; m <<= 1) {
        float ov = __shfl_xor(best, m);
        int   oi = __shfl_xor(bi, m);
        if (ov < best || (ov == best && oi < bi)) { best = ov; bi = oi; }
    }
    if (lane == 0) idx[row] = bi;
}

// ---------------- gather: one wave per row, write both halves ----------------
__global__ void gather_kernel(const float* __restrict__ C,
                              const int* __restrict__ idx,
                              float* __restrict__ out) {
    const size_t half = (size_t)N_ROWS * DIM;
    int gtid = blockIdx.x * blockDim.x + threadIdx.x;
    int lane = threadIdx.x & 63;
    int wave = gtid >> 6;
    int nwaves = (gridDim.x * blockDim.x) >> 6;
    for (int row = wave; row < N_ROWS; row += nwaves) {
        int id = idx[row];
        float4 v = reinterpret_cast<const float4*>(C + (size_t)id * DIM)[lane];
        reinterpret_cast<float4*>(out + (size_t)row * DIM)[lane] = v;
        reinterpret_cast<float4*>(out + half + (size_t)row * DIM)[lane] = v;
    }
}

extern "C" void kernel_launch(void* const* d_in, const int* in_sizes, int n_in,
                              void* d_out, int out_size, void* d_ws, size_t ws_size,
                              hipStream_t stream) {
    const float* z  = (const float*)d_in[0];   // (32,1024,256) fp32
    const float* cb = (const float*)d_in[1];   // (8192,256)    fp32
    float* out = (float*)d_out;

    // big scratch in d_out (fully overwritten by gather at the end):
    char* sc = (char*)d_out;
    unsigned short* A2 = (unsigned short*)(sc);               // 16,777,216 B (xh)
    unsigned short* B2 = (unsigned short*)(sc + 16777216);    //  4,194,304 B (ch)
    float4* partials   = (float4*)(sc + 20971520);            // 16,777,216 B
    float*  rowbound   = (float*)(sc + 37748736);             //    131,072 B

    // small scratch in d_ws:
    float* csq    = (float*)d_ws;                              // 32 KB
    int*   idx    = (int*)((char*)d_ws + 32768);               // 128 KB
    float* cmaxp  = (float*)((char*)d_ws + 163840);            // 32 KB
    float* clmaxp = (float*)((char*)d_ws + 196608);            // 32 KB
    float* cmax   = (float*)((char*)d_ws + 229376);            // 1 KB
    float* clmax  = (float*)((char*)d_ws + 230400);            // 1 KB

    static bool attr_done = false;
    if (!attr_done) {
        hipFuncSetAttribute((const void*)gemm_argmin_kernel,
                            hipFuncAttributeMaxDynamicSharedMemorySize, 131072);
        attr_done = true;
    }

    cmax_kernel<<<32, 256, 0, stream>>>(cb, cmaxp, clmaxp);
    cmax_fold_kernel<<<1, 256, 0, stream>>>(cmaxp, clmaxp, cmax, clmax);
    split_pack_kernel<<<(N_CODES * DIM) / (256 * 8), 256, 0, stream>>>(cb, B2);
    split_x_kernel<<<(N_ROWS * DIM) / (256 * 8), 256, 0, stream>>>(z, A2, cmax, clmax, rowbound);
    csq_kernel<<<(N_CODES * 64) / 256, 256, 0, stream>>>(cb, csq);
    gemm_argmin_kernel<<<4096, 512, 131072, stream>>>(A2, B2, csq, partials);
    resolve_kernel<<<N_ROWS / 4, 256, 0, stream>>>(partials, rowbound, z, cb, csq, idx);
    gather_kernel<<<2048, 256, 0, stream>>>(cb, idx, out);
}

// Round 14
// 345.449 us; speedup vs baseline: 20.9689x; 1.4407x over previous
//
#include <hip/hip_runtime.h>

#define N_ROWS 32768   // BS*SEQ
#define N_CODES 8192
#define DIM 256
#define NSTEP 8        // virtual K = 256, BK = 32 (xh.ch only)

typedef __attribute__((ext_vector_type(8))) short bf16x8;
typedef __attribute__((ext_vector_type(4))) float f32x4;
typedef __attribute__((ext_vector_type(8))) unsigned short u16x8;

#define GLOAD_LDS16(gp, lp) __builtin_amdgcn_global_load_lds( \
    (const __attribute__((address_space(1))) void*)(gp), \
    (__attribute__((address_space(3))) void*)(lp), 16, 0, 0)

#define RD(base, off) (*reinterpret_cast<const bf16x8*>(&(base)[(off)]))

__device__ __forceinline__ unsigned short f2bf_rne(float f) {
    unsigned int u = __float_as_uint(f);
    unsigned int r = (u + 0x7FFFu + ((u >> 16) & 1u)) >> 16;
    return (unsigned short)r;
}
__device__ __forceinline__ float bf2f(unsigned short h) {
    return __uint_as_float(((unsigned int)h) << 16);
}

// ------- per-dim max|c| and max|c - bf16(c)|: 32 partials + deterministic fold
__global__ void cmax_kernel(const float* __restrict__ C,
                            float* __restrict__ cmaxp, float* __restrict__ clmaxp) {
    int t = threadIdx.x;
    float m = 0.f, ml = 0.f;
    const int k0 = blockIdx.x * 256;
    for (int k = k0; k < k0 + 256; ++k) {
        float c = C[(size_t)k * DIM + t];
        m = fmaxf(m, fabsf(c));
        ml = fmaxf(ml, fabsf(c - bf2f(f2bf_rne(c))));
    }
    cmaxp[blockIdx.x * DIM + t] = m;
    clmaxp[blockIdx.x * DIM + t] = ml;
}
__global__ void cmax_fold_kernel(const float* __restrict__ cmaxp,
                                 const float* __restrict__ clmaxp,
                                 float* __restrict__ cmax, float* __restrict__ clmax) {
    int t = threadIdx.x;
    float m = 0.f, ml = 0.f;
    #pragma unroll
    for (int b = 0; b < 32; ++b) {
        m = fmaxf(m, cmaxp[b * DIM + t]);
        ml = fmaxf(ml, clmaxp[b * DIM + t]);
    }
    cmax[t] = m;
    clmax[t] = ml;
}

// ---------------- split codebook fp32 -> ch (bf16, stride 256) ---------------
__global__ void split_pack_kernel(const float* __restrict__ src,
                                  unsigned short* __restrict__ dst) {
    size_t i = ((size_t)blockIdx.x * blockDim.x + threadIdx.x) * 8;
    float4 v0 = *reinterpret_cast<const float4*>(src + i);
    float4 v1 = *reinterpret_cast<const float4*>(src + i + 4);
    float f[8] = {v0.x, v0.y, v0.z, v0.w, v1.x, v1.y, v1.z, v1.w};
    u16x8 h;
    #pragma unroll
    for (int j = 0; j < 8; ++j) h[j] = f2bf_rne(f[j]);
    *reinterpret_cast<u16x8*>(dst + i) = h;
}

// -------- split x -> xh + per-row bound Sum|xl|*cmax + Sum|xh|*clmax ---------
__global__ void split_x_kernel(const float* __restrict__ src,
                               unsigned short* __restrict__ xh,
                               const float* __restrict__ cmax,
                               const float* __restrict__ clmax,
                               float* __restrict__ rowbound) {
    int t = blockIdx.x * blockDim.x + threadIdx.x;
    size_t i = (size_t)t * 8;
    int col = (int)(i & 255);
    float4 v0 = *reinterpret_cast<const float4*>(src + i);
    float4 v1 = *reinterpret_cast<const float4*>(src + i + 4);
    float f[8] = {v0.x, v0.y, v0.z, v0.w, v1.x, v1.y, v1.z, v1.w};
    u16x8 h;
    float s = 0.f;
    #pragma unroll
    for (int j = 0; j < 8; ++j) {
        unsigned short hb = f2bf_rne(f[j]);
        h[j] = hb;
        float hv = bf2f(hb);
        s += fabsf(f[j] - hv) * cmax[col + j] + fabsf(hv) * clmax[col + j];
    }
    *reinterpret_cast<u16x8*>(xh + i) = h;
    #pragma unroll
    for (int m = 1; m < 32; m <<= 1) s += __shfl_xor(s, m);
    if ((threadIdx.x & 31) == 0) rowbound[t >> 5] = s * 1.01f;
}

// ---------------- c_sq: one wave per code ----------------
__global__ void csq_kernel(const float* __restrict__ C, float* __restrict__ csq) {
    int gtid = blockIdx.x * blockDim.x + threadIdx.x;
    int wave = gtid >> 6;
    int lane = threadIdx.x & 63;
    float4 v = reinterpret_cast<const float4*>(C + (size_t)wave * DIM)[lane];
    float s = v.x * v.x + v.y * v.y + v.z * v.z + v.w * v.w;
    #pragma unroll
    for (int m = 32; m; m >>= 1) s += __shfl_xor(s, m);
    if (lane == 0) csq[wave] = s;
}

// K-offset (shorts), BK=32, 8 steps over K=256
__device__ __forceinline__ int AK0(int s) { return (s & 7) * 32; }

// 16 MFMAs of one phase: acc[mb..mb+3][0..3]; A-args = CODE frags, B = ROW frags
#define MFMA16(mb, A0, A1, A2v, A3, B0, B1, B2v, B3)                                \
    acc[mb+0][0] = __builtin_amdgcn_mfma_f32_16x16x32_bf16(A0, B0, acc[mb+0][0], 0, 0, 0); \
    acc[mb+0][1] = __builtin_amdgcn_mfma_f32_16x16x32_bf16(A0, B1, acc[mb+0][1], 0, 0, 0); \
    acc[mb+0][2] = __builtin_amdgcn_mfma_f32_16x16x32_bf16(A0, B2v, acc[mb+0][2], 0, 0, 0); \
    acc[mb+0][3] = __builtin_amdgcn_mfma_f32_16x16x32_bf16(A0, B3, acc[mb+0][3], 0, 0, 0); \
    acc[mb+1][0] = __builtin_amdgcn_mfma_f32_16x16x32_bf16(A1, B0, acc[mb+1][0], 0, 0, 0); \
    acc[mb+1][1] = __builtin_amdgcn_mfma_f32_16x16x32_bf16(A1, B1, acc[mb+1][1], 0, 0, 0); \
    acc[mb+1][2] = __builtin_amdgcn_mfma_f32_16x16x32_bf16(A1, B2v, acc[mb+1][2], 0, 0, 0); \
    acc[mb+1][3] = __builtin_amdgcn_mfma_f32_16x16x32_bf16(A1, B3, acc[mb+1][3], 0, 0, 0); \
    acc[mb+2][0] = __builtin_amdgcn_mfma_f32_16x16x32_bf16(A2v, B0, acc[mb+2][0], 0, 0, 0); \
    acc[mb+2][1] = __builtin_amdgcn_mfma_f32_16x16x32_bf16(A2v, B1, acc[mb+2][1], 0, 0, 0); \
    acc[mb+2][2] = __builtin_amdgcn_mfma_f32_16x16x32_bf16(A2v, B2v, acc[mb+2][2], 0, 0, 0); \
    acc[mb+2][3] = __builtin_amdgcn_mfma_f32_16x16x32_bf16(A2v, B3, acc[mb+2][3], 0, 0, 0); \
    acc[mb+3][0] = __builtin_amdgcn_mfma_f32_16x16x32_bf16(A3, B0, acc[mb+3][0], 0, 0, 0); \
    acc[mb+3][1] = __builtin_amdgcn_mfma_f32_16x16x32_bf16(A3, B1, acc[mb+3][1], 0, 0, 0); \
    acc[mb+3][2] = __builtin_amdgcn_mfma_f32_16x16x32_bf16(A3, B2v, acc[mb+3][2], 0, 0, 0); \
    acc[mb+3][3] = __builtin_amdgcn_mfma_f32_16x16x32_bf16(A3, B3, acc[mb+3][3], 0, 0, 0);

// ------- phase 1: r8 schedule, NSTEP=8, SWAPPED operands (A=codes, B=rows) ---
// acc[m][n]: m = code-tile (wrM*128+m*16+g*4+reg), n = row-tile
// (wcN*64+n*16+lcol). Epilogue: per-row top-2 folds in-register + 2 masks.
__global__ __launch_bounds__(512, 2) void gemm_argmin_kernel(
        const unsigned short* __restrict__ A2,   // [32768][256] xh (rows)
        const unsigned short* __restrict__ B2,   // [8192][256]  ch (codes)
        const float* __restrict__ csq,
        float4* __restrict__ partials) {         // [32768 rows][32 slots]
    extern __shared__ unsigned short S[];        // 131072 B

    const int tid  = threadIdx.x;
    const int w    = tid >> 6;
    const int l    = tid & 63;
    const int wrM  = w >> 2;        // code half (0..1)
    const int wcN  = w & 3;         // row quarter (0..3)
    const int lcol = l & 15;
    const int g    = l >> 4;

    const int swz = (blockIdx.x & 7) * 512 + (blockIdx.x >> 3);
    const int rb  = swz & 127;
    const int cbI = swz >> 7;
    const int rowbase  = rb * 256;
    const int codebase = cbI * 256;

    const int pre   = (l & 7) ^ (l >> 3);
    const int stRow = 2 * (l >> 3) + (pre >> 2);
    const int stK   = (pre & 3) * 8;

    const int lbase = (lcol >> 1) * 64 +
                      (((g + ((lcol & 1) << 2)) ^ ((lcol >> 1) & 7)) * 8);
    const int coff = wrM * 4096 + lbase;   // + m*512 (into codes region)
    const int roff = wcN * 2048 + lbase;   // + n*512 (into rows region)

    f32x4 acc[8][4];
    #pragma unroll
    for (int m = 0; m < 8; ++m)
        #pragma unroll
        for (int n = 0; n < 4; ++n) acc[m][n] = (f32x4){0.f, 0.f, 0.f, 0.f};

    #pragma unroll
    for (int s0 = 0; s0 < 3; ++s0) {
        const int ak = AK0(s0);
        #pragma unroll
        for (int i = 0; i < 2; ++i) {
            const int c = 2 * w + i;
            GLOAD_LDS16(A2 + (size_t)(rowbase + c * 16 + stRow) * 256 + ak + stK,
                        &S[s0 * 8192 + c * 512]);
        }
        #pragma unroll
        for (int i = 0; i < 2; ++i) {
            const int c = 2 * w + i;
            GLOAD_LDS16(B2 + (size_t)(codebase + c * 16 + stRow) * 256 + ak + stK,
                        &S[32768 + s0 * 8192 + c * 512]);
        }
    }
    asm volatile("s_waitcnt vmcnt(8)" ::: "memory");
    __builtin_amdgcn_sched_barrier(0);
    __builtin_amdgcn_s_barrier();

    // prefetch step-0 frags: na* = code frags (B region), nb* = row frags (A)
    bf16x8 na0, na1, na2, na3, nb0, nb1, nb2, nb3;
    {
        const unsigned short* Rb = &S[0];
        const unsigned short* Cb = &S[32768];
        na0 = RD(Cb, coff + 0 * 512); na1 = RD(Cb, coff + 1 * 512);
        na2 = RD(Cb, coff + 2 * 512); na3 = RD(Cb, coff + 3 * 512);
        nb0 = RD(Rb, roff + 0 * 512); nb1 = RD(Rb, roff + 1 * 512);
        nb2 = RD(Rb, roff + 2 * 512); nb3 = RD(Rb, roff + 3 * 512);
    }

    #pragma unroll 1
    for (int so = 0; so < NSTEP; so += 4) {
        #pragma unroll
        for (int k = 0; k < 4; ++k) {
            const int s = so + k;
            const unsigned short* Cb = &S[32768 + k * 8192];
            int sn = s + 3; if (sn >= NSTEP) sn -= NSTEP;  // wrap: dead stage
            const int snk = (k + 3) & 3;
            const int ak = AK0(sn);

            bf16x8 a4 = RD(Cb, coff + 4 * 512);
            bf16x8 a5 = RD(Cb, coff + 5 * 512);
            bf16x8 a6 = RD(Cb, coff + 6 * 512);
            bf16x8 a7 = RD(Cb, coff + 7 * 512);
            asm volatile("s_waitcnt lgkmcnt(4)" ::: "memory");
            __builtin_amdgcn_sched_barrier(0);
            __builtin_amdgcn_s_setprio(1);
            MFMA16(0, na0, na1, na2, na3, nb0, nb1, nb2, nb3);
            __builtin_amdgcn_s_setprio(0);

            #pragma unroll
            for (int i = 0; i < 2; ++i) {
                const int c = 2 * w + i;
                GLOAD_LDS16(A2 + (size_t)(rowbase + c * 16 + stRow) * 256 + ak + stK,
                            &S[snk * 8192 + c * 512]);
            }
            #pragma unroll
            for (int i = 0; i < 2; ++i) {
                const int c = 2 * w + i;
                GLOAD_LDS16(B2 + (size_t)(codebase + c * 16 + stRow) * 256 + ak + stK,
                            &S[32768 + snk * 8192 + c * 512]);
            }

            asm volatile("s_waitcnt lgkmcnt(0)" ::: "memory");
            __builtin_amdgcn_sched_barrier(0);
            __builtin_amdgcn_s_setprio(1);
            MFMA16(4, a4, a5, a6, a7, nb0, nb1, nb2, nb3);
            __builtin_amdgcn_s_setprio(0);

            asm volatile("s_waitcnt vmcnt(8)" ::: "memory");
            __builtin_amdgcn_sched_barrier(0);
            __builtin_amdgcn_s_barrier();

            {
                const unsigned short* Rb2 = &S[((k + 1) & 3) * 8192];
                const unsigned short* Cb2 = &S[32768 + ((k + 1) & 3) * 8192];
                na0 = RD(Cb2, coff + 0 * 512); na1 = RD(Cb2, coff + 1 * 512);
                na2 = RD(Cb2, coff + 2 * 512); na3 = RD(Cb2, coff + 3 * 512);
                nb0 = RD(Rb2, roff + 0 * 512); nb1 = RD(Rb2, roff + 1 * 512);
                nb2 = RD(Rb2, roff + 2 * 512); nb3 = RD(Rb2, roff + 3 * 512);
            }
        }
    }

    asm volatile("s_waitcnt vmcnt(0) lgkmcnt(0)" ::: "memory");
    __builtin_amdgcn_s_barrier();
    asm volatile("" ::: "memory");

    // ---- epilogue (swapped layout): lane&15 = row, (g*4+reg) = code.
    // Per-row top-2: serial over 32 in-thread codes + 2-mask cross-group fold.
    float4* T = reinterpret_cast<float4*>(S);    // [256 rows][2 wrM] = 8 KB
    #pragma unroll
    for (int n = 0; n < 4; ++n) {
        float v1 = 3.4e38f, v2 = 3.4e38f; int i1 = 0x7fffffff;
        #pragma unroll
        for (int m = 0; m < 8; ++m) {
            const int codeb = codebase + wrM * 128 + m * 16 + g * 4;
            #pragma unroll
            for (int r = 0; r < 4; ++r) {
                float d = fmaf(-2.0f, acc[m][n][r], csq[codeb + r]);
                float vmax = fmaxf(d, v1);
                v2 = fminf(v2, vmax);
                bool lt = d < v1;
                v1 = lt ? d : v1;
                i1 = lt ? (codeb + r) : i1;
            }
        }
        #pragma unroll
        for (int mask = 16; mask < 64; mask <<= 1) {
            float ov1 = __shfl_xor(v1, mask);
            float ov2 = __shfl_xor(v2, mask);
            int   oi1 = __shfl_xor(i1, mask);
            float nv2 = fminf(fminf(v2, ov2), fmaxf(v1, ov1));
            bool take = (ov1 < v1) || (ov1 == v1 && oi1 < i1);
            v1 = take ? ov1 : v1;
            i1 = take ? oi1 : i1;
            v2 = nv2;
        }
        if (l < 16)
            T[(wcN * 64 + n * 16 + l) * 2 + wrM] =
                make_float4(v1, v2, __int_as_float(i1), 0.f);
    }
    __syncthreads();
    if (tid < 256) {
        float4 p0 = T[tid * 2 + 0];
        float4 p1 = T[tid * 2 + 1];
        int q0 = __float_as_int(p0.z), q1 = __float_as_int(p1.z);
        float v2 = fminf(fminf(p0.y, p1.y), fmaxf(p0.x, p1.x));
        bool take = (p1.x < p0.x) || (p1.x == p0.x && q1 < q0);
        float v1 = take ? p1.x : p0.x;
        int   i1 = take ? q1 : q0;
        partials[(size_t)(rowbase + tid) * 32 + cbI] =
            make_float4(v1, v2, __int_as_float(i1), 0.f);
    }
}

// ---------------- resolve: one wave per row; in-band candidate refinement ----
__global__ __launch_bounds__(256) void resolve_kernel(
        const float4* __restrict__ partials,     // [32768][32]
        const float* __restrict__ rowbound,
        const float* __restrict__ X, const float* __restrict__ C,
        const float* __restrict__ csq, int* __restrict__ idx) {
    __shared__ float xs[4][DIM];
    const int lane = threadIdx.x & 63;
    const int wv   = threadIdx.x >> 6;
    const int row  = blockIdx.x * 4 + wv;

    float sv1 = 3.4e38f, sv2 = 3.4e38f; int si1 = 0x7fffffff;
    if (lane < 32) {
        float4 p = partials[(size_t)row * 32 + lane];
        sv1 = p.x; sv2 = p.y; si1 = __float_as_int(p.z);
    }
    float v1g = sv1; int i1g = si1;
    #pragma unroll
    for (int m = 1; m < 64; m <<= 1) {
        float ov = __shfl_xor(v1g, m);
        int   oi = __shfl_xor(i1g, m);
        if (ov < v1g || (ov == v1g && oi < i1g)) { v1g = ov; i1g = oi; }
    }
    const float lim = v1g + 4.0f * rowbound[row] + 1e-5f;
    unsigned long long m1 = __ballot((lane < 32) && (sv1 <= lim));
    unsigned long long m2 = __ballot((lane < 32) && (sv2 <= lim));
    if (__popcll(m1) <= 1 && m2 == 0ull) {
        if (lane == 0) idx[row] = i1g;
        return;
    }

    float4 xv = reinterpret_cast<const float4*>(X + (size_t)row * DIM)[lane];
    reinterpret_cast<float4*>(xs[wv])[lane] = xv;

    float best = 3.4e38f; int bi = 0x7fffffff;
    unsigned long long mm = m1;
    while (mm) {
        int s = __ffsll(mm) - 1; mm &= mm - 1;
        int k = __shfl(si1, s);
        float4 cv = reinterpret_cast<const float4*>(C + (size_t)k * DIM)[lane];
        float d = xv.x * cv.x;
        d = fmaf(xv.y, cv.y, d);
        d = fmaf(xv.z, cv.z, d);
        d = fmaf(xv.w, cv.w, d);
        #pragma unroll
        for (int m = 1; m < 64; m <<= 1) d += __shfl_xor(d, m);
        float dist = fmaf(-2.f, d, csq[k]);
        if (dist < best || (dist == best && k < bi)) { best = dist; bi = k; }
    }
    mm = m2;
    while (mm) {
        int s = __ffsll(mm) - 1; mm &= mm - 1;
        const int k0 = s * 256 + lane;
        const float* c0 = C + (size_t)k0 * DIM;
        float d0 = 0.f, d1 = 0.f, d2 = 0.f, d3 = 0.f;
        #pragma unroll 8
        for (int dd = 0; dd < DIM; dd += 4) {
            float4 a  = *reinterpret_cast<const float4*>(&xs[wv][dd]);
            float4 q0 = *reinterpret_cast<const float4*>(c0 + dd);
            float4 q1 = *reinterpret_cast<const float4*>(c0 + 64 * DIM + dd);
            float4 q2 = *reinterpret_cast<const float4*>(c0 + 128 * DIM + dd);
            float4 q3 = *reinterpret_cast<const float4*>(c0 + 192 * DIM + dd);
            d0 = fmaf(a.x,q0.x,d0); d0 = fmaf(a.y,q0.y,d0); d0 = fmaf(a.z,q0.z,d0); d0 = fmaf(a.w,q0.w,d0);
            d1 = fmaf(a.x,q1.x,d1); d1 = fmaf(a.y,q1.y,d1); d1 = fmaf(a.z,q1.z,d1); d1 = fmaf(a.w,q1.w,d1);
            d2 = fmaf(a.x,q2.x,d2); d2 = fmaf(a.y,q2.y,d2); d2 = fmaf(a.z,q2.z,d2); d2 = fmaf(a.w,q2.w,d2);
            d3 = fmaf(a.x,q3.x,d3); d3 = fmaf(a.y,q3.y,d3); d3 = fmaf(a.z,q3.z,d3); d3 = fmaf(a.w,q3.w,d3);
        }
        float e0 = fmaf(-2.f, d0, csq[k0]);
        float e1 = fmaf(-2.f, d1, csq[k0 + 64]);
        float e2 = fmaf(-2.f, d2, csq[k0 + 128]);
        float e3 = fmaf(-2.f, d3, csq[k0 + 192]);
        if (e0 < best || (e0 == best && (k0      ) < bi)) { best = e0; bi = k0; }
        if (e1 < best || (e1 == best && (k0 +  64) < bi)) { best = e1; bi = k0 + 64; }
        if (e2 < best || (e2 == best && (k0 + 128) < bi)) { best = e2; bi = k0 + 128; }
        if (e3 < best || (e3 == best && (k0 + 192) < bi)) { best = e3; bi = k0 + 192; }
    }
    #pragma unroll
    for (int m = 1; m < 64; m <<= 1) {
        float ov = __shfl_xor(best, m);
        int   oi = __shfl_xor(bi, m);
        if (ov < best || (ov == best && oi < bi)) { best = ov; bi = oi; }
    }
    if (lane == 0) idx[row] = bi;
}

// ---------------- gather: one wave per row, write both halves ----------------
__global__ void gather_kernel(const float* __restrict__ C,
                              const int* __restrict__ idx,
                              float* __restrict__ out) {
    const size_t half = (size_t)N_ROWS * DIM;
    int gtid = blockIdx.x * blockDim.x + threadIdx.x;
    int lane = threadIdx.x & 63;
    int wave = gtid >> 6;
    int nwaves = (gridDim.x * blockDim.x) >> 6;
    for (int row = wave; row < N_ROWS; row += nwaves) {
        int id = idx[row];
        float4 v = reinterpret_cast<const float4*>(C + (size_t)id * DIM)[lane];
        reinterpret_cast<float4*>(out + (size_t)row * DIM)[lane] = v;
        reinterpret_cast<float4*>(out + half + (size_t)row * DIM)[lane] = v;
    }
}

extern "C" void kernel_launch(void* const* d_in, const int* in_sizes, int n_in,
                              void* d_out, int out_size, void* d_ws, size_t ws_size,
                              hipStream_t stream) {
    const float* z  = (const float*)d_in[0];   // (32,1024,256) fp32
    const float* cb = (const float*)d_in[1];   // (8192,256)    fp32
    float* out = (float*)d_out;

    // big scratch in d_out (fully overwritten by gather at the end):
    char* sc = (char*)d_out;
    unsigned short* A2 = (unsigned short*)(sc);               // 16,777,216 B (xh)
    unsigned short* B2 = (unsigned short*)(sc + 16777216);    //  4,194,304 B (ch)
    float4* partials   = (float4*)(sc + 20971520);            // 16,777,216 B
    float*  rowbound   = (float*)(sc + 37748736);             //    131,072 B

    // small scratch in d_ws:
    float* csq    = (float*)d_ws;                              // 32 KB
    int*   idx    = (int*)((char*)d_ws + 32768);               // 128 KB
    float* cmaxp  = (float*)((char*)d_ws + 163840);            // 32 KB
    float* clmaxp = (float*)((char*)d_ws + 196608);            // 32 KB
    float* cmax   = (float*)((char*)d_ws + 229376);            // 1 KB
    float* clmax  = (float*)((char*)d_ws + 230400);            // 1 KB

    static bool attr_done = false;
    if (!attr_done) {
        hipFuncSetAttribute((const void*)gemm_argmin_kernel,
                            hipFuncAttributeMaxDynamicSharedMemorySize, 131072);
        attr_done = true;
    }

    cmax_kernel<<<32, 256, 0, stream>>>(cb, cmaxp, clmaxp);
    cmax_fold_kernel<<<1, 256, 0, stream>>>(cmaxp, clmaxp, cmax, clmax);
    split_pack_kernel<<<(N_CODES * DIM) / (256 * 8), 256, 0, stream>>>(cb, B2);
    split_x_kernel<<<(N_ROWS * DIM) / (256 * 8), 256, 0, stream>>>(z, A2, cmax, clmax, rowbound);
    csq_kernel<<<(N_CODES * 64) / 256, 256, 0, stream>>>(cb, csq);
    gemm_argmin_kernel<<<4096, 512, 131072, stream>>>(A2, B2, csq, partials);
    resolve_kernel<<<N_ROWS / 4, 256, 0, stream>>>(partials, rowbound, z, cb, csq, idx);
    gather_kernel<<<2048, 256, 0, stream>>>(cb, idx, out);
}